// Round 1
// baseline (172.074 us; speedup 1.0000x reference)
//
#include <hip/hip_runtime.h>

typedef __attribute__((ext_vector_type(8))) __bf16 bf16x8;
typedef __attribute__((ext_vector_type(8))) unsigned short u16x8;
typedef __attribute__((ext_vector_type(4))) float f32x4;

#define LOG2E 1.4426950408889634f

// async global -> LDS, 16 bytes per lane (dest must be wave-uniform base + lane*16)
#define GLDS16(gp, lp)                                                \
  __builtin_amdgcn_global_load_lds(                                   \
      (const __attribute__((address_space(1))) void*)(gp),            \
      (__attribute__((address_space(3))) void*)(lp), 16, 0, 0)

__device__ __forceinline__ unsigned short f2b(float f) {
  unsigned u = __float_as_uint(f);
  u += 0x7fffu + ((u >> 16) & 1u);   // RNE
  return (unsigned short)(u >> 16);
}
__device__ __forceinline__ float b2f(unsigned short h) {
  return __uint_as_float(((unsigned)h) << 16);
}

// -- 1) fused: xb = bf16(x)  AND  v[b,t,j,d] = sum_i x[b,t,i*64+d]*v_tmp[i*16+j]
__global__ __launch_bounds__(256) void k_xv(const float* __restrict__ x,
                                            const float* __restrict__ vt,
                                            unsigned short* __restrict__ xb,
                                            unsigned short* __restrict__ vb) {
  __shared__ float s_vt[256];
  s_vt[threadIdx.x] = vt[threadIdx.x];
  __syncthreads();
  int g = blockIdx.x * 256 + threadIdx.x;
  int bt = g >> 6, d = g & 63;
  const float* xp = x + (size_t)bt * 1024 + d;
  float xi[16];
#pragma unroll
  for (int i = 0; i < 16; ++i) xi[i] = xp[i * 64];
#pragma unroll
  for (int i = 0; i < 16; ++i) xb[(size_t)bt * 1024 + i * 64 + d] = f2b(xi[i]);
#pragma unroll
  for (int j = 0; j < 16; ++j) {
    float s = 0.f;
#pragma unroll
    for (int i = 0; i < 16; ++i) s += xi[i] * s_vt[i * 16 + j];
    vb[(size_t)bt * 1024 + j * 64 + d] = f2b(s);
  }
}

// ------- 2) W [1024][2048] fp32 -> Wt [2048][1024] bf16 (transposed) --------
__global__ __launch_bounds__(256) void k_trans_w(const float* __restrict__ W,
                                                 unsigned short* __restrict__ Wt) {
  __shared__ unsigned short tile[64][65];
  int n0 = blockIdx.x * 64;
  int k0 = blockIdx.y * 64;
  int tx = threadIdx.x & 63, ty = threadIdx.x >> 6;
#pragma unroll
  for (int r = 0; r < 16; ++r) {
    int kk = ty * 16 + r;
    tile[kk][tx] = f2b(W[(size_t)(k0 + kk) * 2048 + n0 + tx]);
  }
  __syncthreads();
#pragma unroll
  for (int r = 0; r < 16; ++r) {
    int nn = ty * 16 + r;
    Wt[(size_t)(n0 + nn) * 1024 + k0 + tx] = tile[tx][nn];
  }
}

// ---- 3) GEMM: qk[4096][2048] bf16 = xb[4096][1024] @ Wt[2048][1024]^T ------
// R10: m97 pattern — global_load_lds width-16 staging (LDS dest is linear in
// tid: byte offset = c*16), 2 barriers per K-step. Replaces the register
// round-trip (m93-analog, ~517 TF) with DMA (m97, ~874 TF).
__global__ __launch_bounds__(256) void k_gemm_qk(const unsigned short* __restrict__ A,
                                                 const unsigned short* __restrict__ Bt,
                                                 unsigned short* __restrict__ C) {
  __shared__ unsigned short As[128 * 32];
  __shared__ unsigned short Bs[128 * 32];
  const int K = 1024;
  int m0 = blockIdx.x * 128;
  int n0 = blockIdx.y * 128;
  int tid = threadIdx.x;
  int w = tid >> 6, lane = tid & 63;
  int lq = lane & 15, lk8 = (lane >> 4) * 8;
  int wr = (w >> 1) * 64, wc = (w & 1) * 64;
  f32x4 acc[4][4];
#pragma unroll
  for (int i = 0; i < 4; ++i)
#pragma unroll
    for (int j = 0; j < 4; ++j)
#pragma unroll
      for (int r = 0; r < 4; ++r) acc[i][j][r] = 0.f;

  for (int kk = 0; kk < K; kk += 32) {
    __syncthreads();               // previous iteration's LDS reads done
#pragma unroll
    for (int i = 0; i < 2; ++i) {
      int c = tid + 256 * i;
      int row = c >> 2, col = (c & 3) * 8;
      GLDS16(A + (size_t)(m0 + row) * K + kk + col, As + c * 8);
      GLDS16(Bt + (size_t)(n0 + row) * K + kk + col, Bs + c * 8);
    }
    __syncthreads();               // vmcnt(0) drain + barrier: tiles ready
    bf16x8 af[4], bf[4];
#pragma unroll
    for (int i = 0; i < 4; ++i) af[i] = *(const bf16x8*)(As + (wr + i * 16 + lq) * 32 + lk8);
#pragma unroll
    for (int j = 0; j < 4; ++j) bf[j] = *(const bf16x8*)(Bs + (wc + j * 16 + lq) * 32 + lk8);
#pragma unroll
    for (int i = 0; i < 4; ++i)
#pragma unroll
      for (int j = 0; j < 4; ++j)
        acc[i][j] = __builtin_amdgcn_mfma_f32_16x16x32_bf16(af[i], bf[j], acc[i][j], 0, 0, 0);
  }
#pragma unroll
  for (int i = 0; i < 4; ++i)
#pragma unroll
    for (int j = 0; j < 4; ++j)
#pragma unroll
      for (int r = 0; r < 4; ++r) {
        int m = m0 + wr + i * 16 + (lane >> 4) * 4 + r;
        int n = n0 + wc + j * 16 + lq;
        C[(size_t)m * 2048 + n] = f2b(acc[i][j][r]);
      }
}

// ------- 4) vb [2][2048][1024] -> Vt [2][1024][2048]  (t-major for PV) ------
__global__ __launch_bounds__(256) void k_vtrans(const unsigned short* __restrict__ vb,
                                                unsigned short* __restrict__ Vt) {
  __shared__ unsigned short tile[64][65];
  int t0 = blockIdx.x * 64;
  int c0 = blockIdx.y * 64;
  int b = blockIdx.z;
  int tx = threadIdx.x & 63, ty = threadIdx.x >> 6;
#pragma unroll
  for (int r = 0; r < 16; ++r) {
    int tt = ty * 16 + r;
    tile[tt][tx] = vb[((size_t)b * 2048 + t0 + tt) * 1024 + c0 + tx];
  }
  __syncthreads();
#pragma unroll
  for (int r = 0; r < 16; ++r) {
    int cc = ty * 16 + r;
    Vt[((size_t)b * 1024 + c0 + cc) * 2048 + t0 + tx] = tile[tx][cc];
  }
}

// ---------------- 5) causal flash attention with ALiBi ----------------------
// R10: K/V staging via global_load_lds DMA into the double buffer (dest is
// linear: byte offset = tid*16). Removes the register prefetch + 4
// ds_write_b128/thread/tile (−17% LDS traffic, flash is LDS-issue-bound).
// Safety: DMA into buf^1 at tile-top — that buffer's reads finished at the
// previous tile's __syncthreads(); __syncthreads() drains vmcnt(0) before
// s_barrier so DMA data is visible after it. ALiBi bias hoisted out of the
// kt loop (base[s4][r] + c2*k0 per tile). Keeps: R7 pairing {bx,31-bx},
// fixed-shift softmax, ones-column l, XOR-swizzled Pbuf, all-u16 LDS typing.
__global__ __launch_bounds__(256) void k_flash(const unsigned short* __restrict__ qkb, // [2][2048][2048]
                                               const unsigned short* __restrict__ Vt,  // [2][1024][2048]
                                               unsigned short* __restrict__ y) {       // [2][2048][1024]
  __shared__ unsigned short Ks[2][2][64 * 32];   // [buf][half][kg][d32]
  __shared__ unsigned short Vs[2][2][64 * 32];   // [buf][half][d][t32]
  __shared__ unsigned short Pbuf[4][16 * 64];
  int hd = blockIdx.y, b = blockIdx.z;
  int tid = threadIdx.x;
  int w = tid >> 6, lane = tid & 63;
  int quad = lane >> 4, lq = lane & 15, lk8 = quad * 8;
  int rs = tid >> 2, cs = (tid & 3) * 8;         // staging: row / 8-elem chunk
  const size_t rowb = (size_t)b * 2048;
  const size_t vrow = ((size_t)b * 1024 + hd * 64 + rs) * 2048 + cs;
  const size_t krow = ((rowb + rs) << 11) + 1024 + hd * 64 + cs;

  float slope = exp2f(-0.5f * (float)(hd + 1));  // ALiBi, H=16 power-of-2
  const float c1 = 0.125f * LOG2E;               // 1/sqrt(64) * log2(e)
  const float c2 = slope * LOG2E;
  const float SHIFT = 16.0f;                     // fixed softmax shift (log2)

  bf16x8 ones;
#pragma unroll
  for (int i = 0; i < 8; ++i) ones[i] = (__bf16)1.0f;

#pragma unroll 1
  for (int pass = 0; pass < 2; ++pass) {
    int qt = pass ? (31 - (int)blockIdx.x) : (int)blockIdx.x;
    int q0 = qt * 64;
    int qg = q0 + w * 16 + lq;                   // A-frag row (m = lane&15)

    bf16x8 qf0 = *(const bf16x8*)(qkb + ((rowb + qg) << 11) + hd * 64 + lk8);
    bf16x8 qf1 = *(const bf16x8*)(qkb + ((rowb + qg) << 11) + hd * 64 + 32 + lk8);

    int qrow_base = q0 + w * 16 + quad * 4;      // C-layout rows: + r

    // hoisted ALiBi bias: score += base_b[s4][r] + c2*k0
    float base_b[4][4];
#pragma unroll
    for (int s4 = 0; s4 < 4; ++s4)
#pragma unroll
      for (int r = 0; r < 4; ++r)
        base_b[s4][r] = c2 * (float)(s4 * 16 + lq - qrow_base - r) - SHIFT;

    f32x4 o[4], o4;
#pragma unroll
    for (int r = 0; r < 4; ++r) o4[r] = 0.f;
#pragma unroll
    for (int j = 0; j < 4; ++j)
#pragma unroll
      for (int r = 0; r < 4; ++r) o[j][r] = 0.f;

    // ---- prologue: DMA tile 0 into buffer 0 ----
    __syncthreads();                             // prior pass's reads done
    GLDS16(qkb + krow,      &Ks[0][0][rs * 32 + cs]);
    GLDS16(qkb + krow + 32, &Ks[0][1][rs * 32 + cs]);
    GLDS16(Vt + vrow,       &Vs[0][0][rs * 32 + cs]);
    GLDS16(Vt + vrow + 32,  &Vs[0][1][rs * 32 + cs]);
    __syncthreads();                             // vmcnt(0) drain: tile 0 ready
    int cur = 0;

#pragma unroll 1
    for (int kt = 0; kt <= qt; ++kt) {
      int k0 = kt * 64;
      // DMA tile kt+1 into the other buffer (in flight across this tile)
      if (kt < qt) {
        size_t koff = (size_t)(k0 + 64);
        int nxt = cur ^ 1;
        GLDS16(qkb + krow + (koff << 11),      &Ks[nxt][0][rs * 32 + cs]);
        GLDS16(qkb + krow + (koff << 11) + 32, &Ks[nxt][1][rs * 32 + cs]);
        GLDS16(Vt + vrow + koff,               &Vs[nxt][0][rs * 32 + cs]);
        GLDS16(Vt + vrow + koff + 32,          &Vs[nxt][1][rs * 32 + cs]);
      }
      // K fragments from LDS
      bf16x8 kc[4][2];
#pragma unroll
      for (int s4 = 0; s4 < 4; ++s4) {
        u16x8 t0 = *(const u16x8*)(&Ks[cur][0][(s4 * 16 + lq) * 32 + lk8]);
        u16x8 t1 = *(const u16x8*)(&Ks[cur][1][(s4 * 16 + lq) * 32 + lk8]);
        kc[s4][0] = __builtin_bit_cast(bf16x8, t0);
        kc[s4][1] = __builtin_bit_cast(bf16x8, t1);
      }
      // QK^T
      f32x4 S[4];
#pragma unroll
      for (int s4 = 0; s4 < 4; ++s4) {
        f32x4 a;
#pragma unroll
        for (int r = 0; r < 4; ++r) a[r] = 0.f;
        a = __builtin_amdgcn_mfma_f32_16x16x32_bf16(qf0, kc[s4][0], a, 0, 0, 0);
        a = __builtin_amdgcn_mfma_f32_16x16x32_bf16(qf1, kc[s4][1], a, 0, 0, 0);
        S[s4] = a;
      }
      // p = exp2(score - SHIFT); masked cols -> 0
      float bk = c2 * (float)k0;
      float p[4][4];
      if (kt == qt) {
#pragma unroll
        for (int s4 = 0; s4 < 4; ++s4) {
          int kg = k0 + s4 * 16 + lq;
#pragma unroll
          for (int r = 0; r < 4; ++r) {
            int qr = qrow_base + r;
            float v = S[s4][r] * c1 + (base_b[s4][r] + bk);
            v = (kg <= qr) ? v : -1e30f;
            p[s4][r] = exp2f(v);
          }
        }
      } else {
#pragma unroll
        for (int s4 = 0; s4 < 4; ++s4) {
#pragma unroll
          for (int r = 0; r < 4; ++r) {
            float v = S[s4][r] * c1 + (base_b[s4][r] + bk);
            p[s4][r] = exp2f(v);
          }
        }
      }
      // P: C-layout -> LDS (XOR-swizzled) -> A-layout (per-wave, no barrier)
#pragma unroll
      for (int s4 = 0; s4 < 4; ++s4) {
        int cg = (s4 ^ quad) << 4;
#pragma unroll
        for (int r = 0; r < 4; ++r)
          Pbuf[w][(quad * 4 + r) * 64 + cg + lq] = f2b(p[s4][r]);
      }
      int g0 = ((quad >> 1) ^ (lq >> 2)) << 4;
      int g1 = ((2 | (quad >> 1)) ^ (lq >> 2)) << 4;
      int sub = (quad & 1) * 8;
      u16x8 t0 = *(const u16x8*)(&Pbuf[w][lq * 64 + g0 + sub]);
      u16x8 t1 = *(const u16x8*)(&Pbuf[w][lq * 64 + g1 + sub]);
      bf16x8 pf0 = __builtin_bit_cast(bf16x8, t0);
      bf16x8 pf1 = __builtin_bit_cast(bf16x8, t1);
      // V fragments from LDS, then PV + ones-column
#pragma unroll
      for (int j = 0; j < 4; ++j) {
        u16x8 v0 = *(const u16x8*)(&Vs[cur][0][(j * 16 + lq) * 32 + lk8]);
        u16x8 v1 = *(const u16x8*)(&Vs[cur][1][(j * 16 + lq) * 32 + lk8]);
        bf16x8 vf0 = __builtin_bit_cast(bf16x8, v0);
        bf16x8 vf1 = __builtin_bit_cast(bf16x8, v1);
        o[j] = __builtin_amdgcn_mfma_f32_16x16x32_bf16(pf0, vf0, o[j], 0, 0, 0);
        o[j] = __builtin_amdgcn_mfma_f32_16x16x32_bf16(pf1, vf1, o[j], 0, 0, 0);
        if (j == 0) {
          o4 = __builtin_amdgcn_mfma_f32_16x16x32_bf16(pf0, ones, o4, 0, 0, 0);
          o4 = __builtin_amdgcn_mfma_f32_16x16x32_bf16(pf1, ones, o4, 0, 0, 0);
        }
      }
      // switch buffers; DMA for tile kt+1 drains inside __syncthreads()
      if (kt < qt) {
        __syncthreads();
        cur ^= 1;
      }
    }
#pragma unroll
    for (int r = 0; r < 4; ++r) {
      float inv = 1.0f / o4[r];     // l (all cols of ones-acc equal)
      int qr = qrow_base + r;
#pragma unroll
      for (int j = 0; j < 4; ++j)
        y[((rowb + qr) << 10) + hd * 64 + j * 16 + lq] = f2b(o[j][r] * inv);
    }
  }
}

// --- 6) out[b,t,i*64+d] = sum_j y[b,t,j*64+d] * proj_tmp[i*16+j]  (FP32 out) ---
__global__ __launch_bounds__(256) void k_proj(const unsigned short* __restrict__ yb,
                                              const float* __restrict__ pt,
                                              float* __restrict__ out) {
  __shared__ float s_pt[256];
  s_pt[threadIdx.x] = pt[threadIdx.x];
  __syncthreads();
  int g = blockIdx.x * 256 + threadIdx.x;
  int bt = g >> 6, d = g & 63;
  float yj[16];
#pragma unroll
  for (int j = 0; j < 16; ++j) yj[j] = b2f(yb[(size_t)bt * 1024 + j * 64 + d]);
#pragma unroll
  for (int i = 0; i < 16; ++i) {
    float s = 0.f;
#pragma unroll
    for (int j = 0; j < 16; ++j) s += yj[j] * s_pt[i * 16 + j];
    out[(size_t)bt * 1024 + i * 64 + d] = s;
  }
}

extern "C" void kernel_launch(void* const* d_in, const int* in_sizes, int n_in,
                              void* d_out, int out_size, void* d_ws, size_t ws_size,
                              hipStream_t stream) {
  const float* x  = (const float*)d_in[0];   // [2][2048][1024] fp32
  const float* W  = (const float*)d_in[1];   // [1024][2048] fp32
  const float* vt = (const float*)d_in[2];   // [16][16] fp32
  const float* pt = (const float*)d_in[3];   // [16][16] fp32
  float* out = (float*)d_out;                // fp32 out

  char* ws = (char*)d_ws;
  unsigned short* xb  = (unsigned short*)(ws);                 //  8 MiB, reused as y
  unsigned short* Wt  = (unsigned short*)(ws + (8u  << 20));   //  4 MiB
  unsigned short* qkb = (unsigned short*)(ws + (12u << 20));   // 16 MiB
  unsigned short* vb  = (unsigned short*)(ws + (28u << 20));   //  8 MiB
  unsigned short* Vtr = (unsigned short*)(ws + (36u << 20));   //  8 MiB
  unsigned short* yb  = xb;  // xb dead after GEMM; flash writes y there

  k_xv     <<<1024, 256, 0, stream>>>(x, vt, xb, vb);
  k_trans_w<<<dim3(32, 16), 256, 0, stream>>>(W, Wt);
  k_gemm_qk<<<dim3(32, 16), 256, 0, stream>>>(xb, Wt, qkb);
  k_vtrans <<<dim3(32, 16, 2), 256, 0, stream>>>(vb, Vtr);
  k_flash  <<<dim3(16, 16, 2), 256, 0, stream>>>(qkb, Vtr, yb);
  k_proj   <<<1024, 256, 0, stream>>>(yb, pt, out);
}

// Round 2
// 164.941 us; speedup vs baseline: 1.0432x; 1.0432x over previous
//
#include <hip/hip_runtime.h>

typedef __attribute__((ext_vector_type(8))) __bf16 bf16x8;
typedef __attribute__((ext_vector_type(8))) unsigned short u16x8;
typedef __attribute__((ext_vector_type(4))) float f32x4;

#define LOG2E 1.4426950408889634f

// async global -> LDS, 16 bytes per lane (dest must be wave-uniform base + lane*16)
#define GLDS16(gp, lp)                                                \
  __builtin_amdgcn_global_load_lds(                                   \
      (const __attribute__((address_space(1))) void*)(gp),            \
      (__attribute__((address_space(3))) void*)(lp), 16, 0, 0)

// R11: native cast — compiler emits v_cvt_pk_bf16_f32 (RNE), replacing the
// 4-instr manual round (learn_hip m240: scalar casts beat hand-written seq).
__device__ __forceinline__ unsigned short f2b(float f) {
  return __builtin_bit_cast(unsigned short, (__bf16)f);
}
__device__ __forceinline__ float b2f(unsigned short h) {
  return __uint_as_float(((unsigned)h) << 16);
}

// -- 1) fused: xb = bf16(x)  AND  v[b,t,j,d] = sum_i x[b,t,i*64+d]*v_tmp[i*16+j]
__global__ __launch_bounds__(256) void k_xv(const float* __restrict__ x,
                                            const float* __restrict__ vt,
                                            unsigned short* __restrict__ xb,
                                            unsigned short* __restrict__ vb) {
  __shared__ float s_vt[256];
  s_vt[threadIdx.x] = vt[threadIdx.x];
  __syncthreads();
  int g = blockIdx.x * 256 + threadIdx.x;
  int bt = g >> 6, d = g & 63;
  const float* xp = x + (size_t)bt * 1024 + d;
  float xi[16];
#pragma unroll
  for (int i = 0; i < 16; ++i) xi[i] = xp[i * 64];
#pragma unroll
  for (int i = 0; i < 16; ++i) xb[(size_t)bt * 1024 + i * 64 + d] = f2b(xi[i]);
#pragma unroll
  for (int j = 0; j < 16; ++j) {
    float s = 0.f;
#pragma unroll
    for (int i = 0; i < 16; ++i) s += xi[i] * s_vt[i * 16 + j];
    vb[(size_t)bt * 1024 + j * 64 + d] = f2b(s);
  }
}

// ------- 2) W [1024][2048] fp32 -> Wt [2048][1024] bf16 (transposed) --------
__global__ __launch_bounds__(256) void k_trans_w(const float* __restrict__ W,
                                                 unsigned short* __restrict__ Wt) {
  __shared__ unsigned short tile[64][65];
  int n0 = blockIdx.x * 64;
  int k0 = blockIdx.y * 64;
  int tx = threadIdx.x & 63, ty = threadIdx.x >> 6;
#pragma unroll
  for (int r = 0; r < 16; ++r) {
    int kk = ty * 16 + r;
    tile[kk][tx] = f2b(W[(size_t)(k0 + kk) * 2048 + n0 + tx]);
  }
  __syncthreads();
#pragma unroll
  for (int r = 0; r < 16; ++r) {
    int nn = ty * 16 + r;
    Wt[(size_t)(n0 + nn) * 1024 + k0 + tx] = tile[tx][nn];
  }
}

// ---- 3) GEMM: qk[4096][2048] bf16 = xb[4096][1024] @ Wt[2048][1024]^T ------
// m97 pattern — global_load_lds width-16 staging, 2 barriers per K-step.
__global__ __launch_bounds__(256) void k_gemm_qk(const unsigned short* __restrict__ A,
                                                 const unsigned short* __restrict__ Bt,
                                                 unsigned short* __restrict__ C) {
  __shared__ unsigned short As[128 * 32];
  __shared__ unsigned short Bs[128 * 32];
  const int K = 1024;
  int m0 = blockIdx.x * 128;
  int n0 = blockIdx.y * 128;
  int tid = threadIdx.x;
  int w = tid >> 6, lane = tid & 63;
  int lq = lane & 15, lk8 = (lane >> 4) * 8;
  int wr = (w >> 1) * 64, wc = (w & 1) * 64;
  f32x4 acc[4][4];
#pragma unroll
  for (int i = 0; i < 4; ++i)
#pragma unroll
    for (int j = 0; j < 4; ++j)
#pragma unroll
      for (int r = 0; r < 4; ++r) acc[i][j][r] = 0.f;

  for (int kk = 0; kk < K; kk += 32) {
    __syncthreads();               // previous iteration's LDS reads done
#pragma unroll
    for (int i = 0; i < 2; ++i) {
      int c = tid + 256 * i;
      int row = c >> 2, col = (c & 3) * 8;
      GLDS16(A + (size_t)(m0 + row) * K + kk + col, As + c * 8);
      GLDS16(Bt + (size_t)(n0 + row) * K + kk + col, Bs + c * 8);
    }
    __syncthreads();               // vmcnt(0) drain + barrier: tiles ready
    bf16x8 af[4], bf[4];
#pragma unroll
    for (int i = 0; i < 4; ++i) af[i] = *(const bf16x8*)(As + (wr + i * 16 + lq) * 32 + lk8);
#pragma unroll
    for (int j = 0; j < 4; ++j) bf[j] = *(const bf16x8*)(Bs + (wc + j * 16 + lq) * 32 + lk8);
#pragma unroll
    for (int i = 0; i < 4; ++i)
#pragma unroll
      for (int j = 0; j < 4; ++j)
        acc[i][j] = __builtin_amdgcn_mfma_f32_16x16x32_bf16(af[i], bf[j], acc[i][j], 0, 0, 0);
  }
#pragma unroll
  for (int i = 0; i < 4; ++i)
#pragma unroll
    for (int j = 0; j < 4; ++j)
#pragma unroll
      for (int r = 0; r < 4; ++r) {
        int m = m0 + wr + i * 16 + (lane >> 4) * 4 + r;
        int n = n0 + wc + j * 16 + lq;
        C[(size_t)m * 2048 + n] = f2b(acc[i][j][r]);
      }
}

// ------- 4) vb [2][2048][1024] -> Vt [2][1024][2048]  (t-major for PV) ------
__global__ __launch_bounds__(256) void k_vtrans(const unsigned short* __restrict__ vb,
                                                unsigned short* __restrict__ Vt) {
  __shared__ unsigned short tile[64][65];
  int t0 = blockIdx.x * 64;
  int c0 = blockIdx.y * 64;
  int b = blockIdx.z;
  int tx = threadIdx.x & 63, ty = threadIdx.x >> 6;
#pragma unroll
  for (int r = 0; r < 16; ++r) {
    int tt = ty * 16 + r;
    tile[tt][tx] = vb[((size_t)b * 2048 + t0 + tt) * 1024 + c0 + tx];
  }
  __syncthreads();
#pragma unroll
  for (int r = 0; r < 16; ++r) {
    int cc = ty * 16 + r;
    Vt[((size_t)b * 1024 + c0 + cc) * 2048 + t0 + tx] = tile[tx][cc];
  }
}

// ---------------- 5) causal flash attention with ALiBi ----------------------
// R11: XCD-group swizzle — 1D grid of 512, decoded so the 16 pair-blocks
// sharing one (hd,b) K/V stream land on the SAME XCD (id ≡ group mod 8).
// Per-XCD working set: 4 groups x ~1 MiB (K/V re-read part 2 MiB) < 4 MiB L2,
// so the per-tile DMA prefetch hits L2 (~200 cyc) instead of HBM (~900 cyc)
// and drains inside the compute window. R10 kept: global_load_lds double
// buffer, hoisted ALiBi bias, pairing {j, 31-j}, fixed-shift softmax,
// ones-column l, XOR-swizzled Pbuf, all-u16 LDS typing.
__global__ __launch_bounds__(256) void k_flash(const unsigned short* __restrict__ qkb, // [2][2048][2048]
                                               const unsigned short* __restrict__ Vt,  // [2][1024][2048]
                                               unsigned short* __restrict__ y) {       // [2][2048][1024]
  __shared__ unsigned short Ks[2][2][64 * 32];   // [buf][half][kg][d32]
  __shared__ unsigned short Vs[2][2][64 * 32];   // [buf][half][d][t32]
  __shared__ unsigned short Pbuf[4][16 * 64];
  // ---- XCD-group decode: id = xcd + 8*((g>>3)*16 + j), g = (b<<4)|hd ----
  int id = blockIdx.x;
  int xcd = id & 7, s = id >> 3;
  int g = xcd + 8 * (s >> 4);                    // group 0..31 (same-XCD sharers)
  int j = s & 15;                                // pair index within group
  int hd = g & 15, b = g >> 4;
  int tid = threadIdx.x;
  int w = tid >> 6, lane = tid & 63;
  int quad = lane >> 4, lq = lane & 15, lk8 = quad * 8;
  int rs = tid >> 2, cs = (tid & 3) * 8;         // staging: row / 8-elem chunk
  const size_t rowb = (size_t)b * 2048;
  const size_t vrow = ((size_t)b * 1024 + hd * 64 + rs) * 2048 + cs;
  const size_t krow = ((rowb + rs) << 11) + 1024 + hd * 64 + cs;

  float slope = exp2f(-0.5f * (float)(hd + 1));  // ALiBi, H=16 power-of-2
  const float c1 = 0.125f * LOG2E;               // 1/sqrt(64) * log2(e)
  const float c2 = slope * LOG2E;
  const float SHIFT = 16.0f;                     // fixed softmax shift (log2)

  bf16x8 ones;
#pragma unroll
  for (int i = 0; i < 8; ++i) ones[i] = (__bf16)1.0f;

#pragma unroll 1
  for (int pass = 0; pass < 2; ++pass) {
    int qt = pass ? (31 - j) : j;
    int q0 = qt * 64;
    int qg = q0 + w * 16 + lq;                   // A-frag row (m = lane&15)

    bf16x8 qf0 = *(const bf16x8*)(qkb + ((rowb + qg) << 11) + hd * 64 + lk8);
    bf16x8 qf1 = *(const bf16x8*)(qkb + ((rowb + qg) << 11) + hd * 64 + 32 + lk8);

    int qrow_base = q0 + w * 16 + quad * 4;      // C-layout rows: + r

    // hoisted ALiBi bias: score += base_b[s4][r] + c2*k0
    float base_b[4][4];
#pragma unroll
    for (int s4 = 0; s4 < 4; ++s4)
#pragma unroll
      for (int r = 0; r < 4; ++r)
        base_b[s4][r] = c2 * (float)(s4 * 16 + lq - qrow_base - r) - SHIFT;

    f32x4 o[4], o4;
#pragma unroll
    for (int r = 0; r < 4; ++r) o4[r] = 0.f;
#pragma unroll
    for (int jj = 0; jj < 4; ++jj)
#pragma unroll
      for (int r = 0; r < 4; ++r) o[jj][r] = 0.f;

    // ---- prologue: DMA tile 0 into buffer 0 ----
    __syncthreads();                             // prior pass's reads done
    GLDS16(qkb + krow,      &Ks[0][0][rs * 32 + cs]);
    GLDS16(qkb + krow + 32, &Ks[0][1][rs * 32 + cs]);
    GLDS16(Vt + vrow,       &Vs[0][0][rs * 32 + cs]);
    GLDS16(Vt + vrow + 32,  &Vs[0][1][rs * 32 + cs]);
    __syncthreads();                             // vmcnt(0) drain: tile 0 ready
    int cur = 0;

#pragma unroll 1
    for (int kt = 0; kt <= qt; ++kt) {
      int k0 = kt * 64;
      // DMA tile kt+1 into the other buffer (in flight across this tile)
      if (kt < qt) {
        size_t koff = (size_t)(k0 + 64);
        int nxt = cur ^ 1;
        GLDS16(qkb + krow + (koff << 11),      &Ks[nxt][0][rs * 32 + cs]);
        GLDS16(qkb + krow + (koff << 11) + 32, &Ks[nxt][1][rs * 32 + cs]);
        GLDS16(Vt + vrow + koff,               &Vs[nxt][0][rs * 32 + cs]);
        GLDS16(Vt + vrow + koff + 32,          &Vs[nxt][1][rs * 32 + cs]);
      }
      // K fragments from LDS
      bf16x8 kc[4][2];
#pragma unroll
      for (int s4 = 0; s4 < 4; ++s4) {
        u16x8 t0 = *(const u16x8*)(&Ks[cur][0][(s4 * 16 + lq) * 32 + lk8]);
        u16x8 t1 = *(const u16x8*)(&Ks[cur][1][(s4 * 16 + lq) * 32 + lk8]);
        kc[s4][0] = __builtin_bit_cast(bf16x8, t0);
        kc[s4][1] = __builtin_bit_cast(bf16x8, t1);
      }
      // QK^T
      f32x4 S[4];
#pragma unroll
      for (int s4 = 0; s4 < 4; ++s4) {
        f32x4 a;
#pragma unroll
        for (int r = 0; r < 4; ++r) a[r] = 0.f;
        a = __builtin_amdgcn_mfma_f32_16x16x32_bf16(qf0, kc[s4][0], a, 0, 0, 0);
        a = __builtin_amdgcn_mfma_f32_16x16x32_bf16(qf1, kc[s4][1], a, 0, 0, 0);
        S[s4] = a;
      }
      // p = exp2(score - SHIFT); masked cols -> 0
      float bk = c2 * (float)k0;
      float p[4][4];
      if (kt == qt) {
#pragma unroll
        for (int s4 = 0; s4 < 4; ++s4) {
          int kg = k0 + s4 * 16 + lq;
#pragma unroll
          for (int r = 0; r < 4; ++r) {
            int qr = qrow_base + r;
            float v = S[s4][r] * c1 + (base_b[s4][r] + bk);
            v = (kg <= qr) ? v : -1e30f;
            p[s4][r] = exp2f(v);
          }
        }
      } else {
#pragma unroll
        for (int s4 = 0; s4 < 4; ++s4) {
#pragma unroll
          for (int r = 0; r < 4; ++r) {
            float v = S[s4][r] * c1 + (base_b[s4][r] + bk);
            p[s4][r] = exp2f(v);
          }
        }
      }
      // P: C-layout -> LDS (XOR-swizzled) -> A-layout (per-wave, no barrier)
#pragma unroll
      for (int s4 = 0; s4 < 4; ++s4) {
        int cg = (s4 ^ quad) << 4;
#pragma unroll
        for (int r = 0; r < 4; ++r)
          Pbuf[w][(quad * 4 + r) * 64 + cg + lq] = f2b(p[s4][r]);
      }
      int g0 = ((quad >> 1) ^ (lq >> 2)) << 4;
      int g1 = ((2 | (quad >> 1)) ^ (lq >> 2)) << 4;
      int sub = (quad & 1) * 8;
      u16x8 t0 = *(const u16x8*)(&Pbuf[w][lq * 64 + g0 + sub]);
      u16x8 t1 = *(const u16x8*)(&Pbuf[w][lq * 64 + g1 + sub]);
      bf16x8 pf0 = __builtin_bit_cast(bf16x8, t0);
      bf16x8 pf1 = __builtin_bit_cast(bf16x8, t1);
      // V fragments from LDS, then PV + ones-column
#pragma unroll
      for (int jj = 0; jj < 4; ++jj) {
        u16x8 v0 = *(const u16x8*)(&Vs[cur][0][(jj * 16 + lq) * 32 + lk8]);
        u16x8 v1 = *(const u16x8*)(&Vs[cur][1][(jj * 16 + lq) * 32 + lk8]);
        bf16x8 vf0 = __builtin_bit_cast(bf16x8, v0);
        bf16x8 vf1 = __builtin_bit_cast(bf16x8, v1);
        o[jj] = __builtin_amdgcn_mfma_f32_16x16x32_bf16(pf0, vf0, o[jj], 0, 0, 0);
        o[jj] = __builtin_amdgcn_mfma_f32_16x16x32_bf16(pf1, vf1, o[jj], 0, 0, 0);
        if (jj == 0) {
          o4 = __builtin_amdgcn_mfma_f32_16x16x32_bf16(pf0, ones, o4, 0, 0, 0);
          o4 = __builtin_amdgcn_mfma_f32_16x16x32_bf16(pf1, ones, o4, 0, 0, 0);
        }
      }
      // switch buffers; DMA for tile kt+1 drains inside __syncthreads()
      if (kt < qt) {
        __syncthreads();
        cur ^= 1;
      }
    }
#pragma unroll
    for (int r = 0; r < 4; ++r) {
      float inv = 1.0f / o4[r];     // l (all cols of ones-acc equal)
      int qr = qrow_base + r;
#pragma unroll
      for (int jj = 0; jj < 4; ++jj)
        y[((rowb + qr) << 10) + hd * 64 + jj * 16 + lq] = f2b(o[jj][r] * inv);
    }
  }
}

// --- 6) out[b,t,i*64+d] = sum_j y[b,t,j*64+d] * proj_tmp[i*16+j]  (FP32 out) ---
__global__ __launch_bounds__(256) void k_proj(const unsigned short* __restrict__ yb,
                                              const float* __restrict__ pt,
                                              float* __restrict__ out) {
  __shared__ float s_pt[256];
  s_pt[threadIdx.x] = pt[threadIdx.x];
  __syncthreads();
  int g = blockIdx.x * 256 + threadIdx.x;
  int bt = g >> 6, d = g & 63;
  float yj[16];
#pragma unroll
  for (int j = 0; j < 16; ++j) yj[j] = b2f(yb[(size_t)bt * 1024 + j * 64 + d]);
#pragma unroll
  for (int i = 0; i < 16; ++i) {
    float s = 0.f;
#pragma unroll
    for (int j = 0; j < 16; ++j) s += yj[j] * s_pt[i * 16 + j];
    out[(size_t)bt * 1024 + i * 64 + d] = s;
  }
}

extern "C" void kernel_launch(void* const* d_in, const int* in_sizes, int n_in,
                              void* d_out, int out_size, void* d_ws, size_t ws_size,
                              hipStream_t stream) {
  const float* x  = (const float*)d_in[0];   // [2][2048][1024] fp32
  const float* W  = (const float*)d_in[1];   // [1024][2048] fp32
  const float* vt = (const float*)d_in[2];   // [16][16] fp32
  const float* pt = (const float*)d_in[3];   // [16][16] fp32
  float* out = (float*)d_out;                // fp32 out

  char* ws = (char*)d_ws;
  unsigned short* xb  = (unsigned short*)(ws);                 //  8 MiB, reused as y
  unsigned short* Wt  = (unsigned short*)(ws + (8u  << 20));   //  4 MiB
  unsigned short* qkb = (unsigned short*)(ws + (12u << 20));   // 16 MiB
  unsigned short* vb  = (unsigned short*)(ws + (28u << 20));   //  8 MiB
  unsigned short* Vtr = (unsigned short*)(ws + (36u << 20));   //  8 MiB
  unsigned short* yb  = xb;  // xb dead after GEMM; flash writes y there

  k_xv     <<<1024, 256, 0, stream>>>(x, vt, xb, vb);
  k_trans_w<<<dim3(32, 16), 256, 0, stream>>>(W, Wt);
  k_gemm_qk<<<dim3(32, 16), 256, 0, stream>>>(xb, Wt, qkb);
  k_vtrans <<<dim3(32, 16, 2), 256, 0, stream>>>(vb, Vtr);
  k_flash  <<<512, 256, 0, stream>>>(qkb, Vtr, yb);
  k_proj   <<<1024, 256, 0, stream>>>(yb, pt, out);
}